// Round 11
// baseline (117.431 us; speedup 1.0000x reference)
//
#include <hip/hip_runtime.h>

#define SDIM 65536
#define BDIM 32
#define RDIM 128
#define NDEG 4
#define NCHUNK 512
#define CHUNK_S 128               /* s-rows per chunk */
#define NSTEP (CHUNK_S / 16)      /* 8 double-buffer steps of 16 rows */
#define MTOT (BDIM * SDIM)        /* 2097152 */
#define EPS_BN 1e-5f
#define NSTATB 512                /* k_stats grid */
#define TSLICE (NDEG * BDIM * RDIM)  /* 16384 floats per chunk slice */

// ---------------- K1a: per-block partial stats (no atomics, no init needed) ----
__global__ void k_stats(const float* __restrict__ x, float* __restrict__ partial) {
    __shared__ float s_sum[256];
    __shared__ float s_sq[256];
    int tid = threadIdx.x;
    int gid = blockIdx.x * 256 + tid;
    int stride = gridDim.x * 256;
    float sum = 0.f, sq = 0.f;
    const float4* x4 = (const float4*)x;
    for (int i = gid; i < MTOT / 4; i += stride) {
        float4 v = x4[i];
        sum += (v.x + v.y) + (v.z + v.w);
        sq  += (v.x * v.x + v.y * v.y) + (v.z * v.z + v.w * v.w);
    }
    s_sum[tid] = sum; s_sq[tid] = sq;
    __syncthreads();
    for (int off = 128; off > 0; off >>= 1) {
        if (tid < off) { s_sum[tid] += s_sum[tid + off]; s_sq[tid] += s_sq[tid + off]; }
        __syncthreads();
    }
    if (tid == 0) { partial[blockIdx.x * 2] = s_sum[0]; partial[blockIdx.x * 2 + 1] = s_sq[0]; }
}

// ---------------- K1b: finalize stats (1 block) ----------------
__global__ void k_stats_fin(const float* __restrict__ partial, float* __restrict__ stats) {
    __shared__ float s_sum[256];
    __shared__ float s_sq[256];
    int tid = threadIdx.x;
    float sum = partial[tid * 2] + partial[(tid + 256) * 2];
    float sq  = partial[tid * 2 + 1] + partial[(tid + 256) * 2 + 1];
    s_sum[tid] = sum; s_sq[tid] = sq;
    __syncthreads();
    for (int off = 128; off > 0; off >>= 1) {
        if (tid < off) { s_sum[tid] += s_sum[tid + off]; s_sq[tid] += s_sq[tid + off]; }
        __syncthreads();
    }
    if (tid == 0) { stats[0] = s_sum[0]; stats[1] = s_sq[0]; }
}

// ---------------- K2: normalize + transpose -> zT[s][b], LDS tiled ----------------
__global__ void __launch_bounds__(256) k_norm_t(const float* __restrict__ x,
                                                const float* __restrict__ gamma,
                                                const float* __restrict__ bnb,
                                                const float* __restrict__ stats,
                                                float* __restrict__ zT) {
    __shared__ float lds[64][33];   // pad to kill bank conflicts
    int tid = threadIdx.x;
    int s0 = blockIdx.x * 64;
    float mean = stats[0] * (1.f / MTOT);
    float var  = stats[1] * (1.f / MTOT) - mean * mean;
    float istd = rsqrtf(var + EPS_BN);
    float a  = gamma[0] * istd;
    float c0 = bnb[0] - mean * a;

    int sl = tid & 63, bq = tid >> 6;     // load phase: lane along s (coalesced)
#pragma unroll
    for (int k = 0; k < 8; ++k) {
        int b = k * 4 + bq;
        lds[sl][b] = fmaf(a, x[(size_t)b * SDIM + s0 + sl], c0);
    }
    __syncthreads();
    int bl = tid & 31, sq = tid >> 5;     // store phase: lane along b (coalesced)
#pragma unroll
    for (int k = 0; k < 8; ++k) {
        int s = k * 8 + sq;
        zT[(size_t)(s0 + s) * BDIM + bl] = lds[s][bl];
    }
}

// async global->LDS, 16B per lane, compiler-tracked in vmcnt (drained at barriers)
#define GLL(gp, lp) __builtin_amdgcn_global_load_lds( \
    (const __attribute__((address_space(1))) void*)(gp), \
    (__attribute__((address_space(3))) void*)(lp), 16, 0, 0)

// ---------------- K3: outer-product GEMM, 4b x 8r tile, 2 s-planes ----------------
// Block = (chunk, n), 256 thr = 2 s-planes x (8 b-quads x 16 r-groups).
// Thread r-set: {4p..4p+3, 64+4p..64+4p+3} (2-way LDS bank alias = free).
// U double-buffered via global_load_lds (16-row tiles); z staged once.
// LDS bytes/FMA = 1.5 (was 2.0) -> ~31us LDS floor.
__global__ void __launch_bounds__(256) k_gemm_t(const float* __restrict__ zT,
                                                const float* __restrict__ U,
                                                float* __restrict__ t_part) {
    __shared__ float z_lds[CHUNK_S * BDIM];   // 16 KB
    __shared__ float u_lds[2][16 * RDIM];     // 2 x 8 KB
    int tid = threadIdx.x;
    int pl  = tid >> 7;           // s-plane 0/1
    int t7  = tid & 127;
    int o   = t7 >> 4;            // b-quad 0..7 (b = 4o..4o+3)
    int p   = t7 & 15;            // r-group
    int chunk = blockIdx.x;       // 0..NCHUNK-1
    int n     = blockIdx.y;       // 0..NDEG-1
    size_t s0 = (size_t)chunk * CHUNK_S;

    // stage z chunk (16 KB, coalesced float4)
    {
        const float4* src = (const float4*)(zT + s0 * BDIM);
        float4* dst = (float4*)z_lds;
#pragma unroll
        for (int i = 0; i < (CHUNK_S * BDIM / 4) / 256; ++i)
            dst[i * 256 + tid] = src[i * 256 + tid];
    }

    const float* Ut = U + (size_t)n * SDIM * RDIM + s0 * RDIM;
    // prologue: stage U step 0 (8 KB = 2 GLL calls/thread, linear)
    {
        const float* gp = Ut + tid * 4;
        float* lp = &u_lds[0][0] + tid * 4;
        GLL(gp, lp);
        GLL(gp + 1024, lp + 1024);
    }
    __syncthreads();

    float acc[4][8];
#pragma unroll
    for (int j = 0; j < 4; ++j)
#pragma unroll
        for (int k = 0; k < 8; ++k) acc[j][k] = 0.f;

    for (int t = 0; t < NSTEP; ++t) {
        if (t + 1 < NSTEP) {   // prefetch next 16-row U tile
            const float* gp = Ut + (size_t)(t + 1) * 16 * RDIM + tid * 4;
            float* lp = &u_lds[(t + 1) & 1][0] + tid * 4;
            GLL(gp, lp);
            GLL(gp + 1024, lp + 1024);
        }
        const float* ubase = u_lds[t & 1];
        const float* zbase = z_lds + (size_t)t * 16 * BDIM;
#pragma unroll
        for (int rr = 0; rr < 8; ++rr) {
            int rl = 8 * pl + rr;   // row within step (plane-split)
            float4 z4  = *(const float4*)(zbase + rl * BDIM + 4 * o);
            float4 ua4 = *(const float4*)(ubase + rl * RDIM + 4 * p);
            float4 ub4 = *(const float4*)(ubase + rl * RDIM + 64 + 4 * p);
#pragma unroll
            for (int j = 0; j < 4; ++j) {
                float zj = (j == 0) ? z4.x : (j == 1) ? z4.y : (j == 2) ? z4.z : z4.w;
                acc[j][0] = fmaf(zj, ua4.x, acc[j][0]);
                acc[j][1] = fmaf(zj, ua4.y, acc[j][1]);
                acc[j][2] = fmaf(zj, ua4.z, acc[j][2]);
                acc[j][3] = fmaf(zj, ua4.w, acc[j][3]);
                acc[j][4] = fmaf(zj, ub4.x, acc[j][4]);
                acc[j][5] = fmaf(zj, ub4.y, acc[j][5]);
                acc[j][6] = fmaf(zj, ub4.z, acc[j][6]);
                acc[j][7] = fmaf(zj, ub4.w, acc[j][7]);
            }
        }
        __syncthreads();   // drains GLL (compiler vmcnt) + protects buffer reuse
    }

    // combine the two s-planes via LDS (reuse u_lds region: 16 KB = 4096 floats)
    float* cm = &u_lds[0][0];
    if (pl == 1) {
#pragma unroll
        for (int j = 0; j < 4; ++j)
#pragma unroll
            for (int k = 0; k < 8; ++k)
                cm[t7 * 32 + j * 8 + k] = acc[j][k];
    }
    __syncthreads();
    if (pl == 0) {
        float* outp = t_part + ((size_t)chunk * NDEG + n) * (BDIM * RDIM);
#pragma unroll
        for (int j = 0; j < 4; ++j) {
#pragma unroll
            for (int k = 0; k < 8; ++k) acc[j][k] += cm[t7 * 32 + j * 8 + k];
            int b = 4 * o + j;
            *(float4*)(outp + b * RDIM + 4 * p) =
                make_float4(acc[j][0], acc[j][1], acc[j][2], acc[j][3]);
            *(float4*)(outp + b * RDIM + 64 + 4 * p) =
                make_float4(acc[j][4], acc[j][5], acc[j][6], acc[j][7]);
        }
    }
}

// ---------------- K4a: reduce 8-chunk groups, fully coalesced float4 ----------------
// grid (64 groups, 4 strips); block strip covers 1024 float4 of the 4096-f4 slice
__global__ void __launch_bounds__(256) k_reduce_a(const float* __restrict__ t_part,
                                                  float* __restrict__ t_mid) {
    int tid = threadIdx.x;
    int j = blockIdx.x;          // chunk group 0..63 (8 chunks each)
    int strip = blockIdx.y;      // 0..3
    const float4* tp4 = (const float4*)t_part;
    float4* tm4 = (float4*)t_mid;
#pragma unroll
    for (int e = 0; e < 4; ++e) {
        int idx = strip * 1024 + e * 256 + tid;   // 0..4095 within slice
        float4 s = make_float4(0.f, 0.f, 0.f, 0.f);
#pragma unroll
        for (int c = 0; c < 8; ++c) {
            float4 v = tp4[(size_t)(8 * j + c) * (TSLICE / 4) + idx];
            s.x += v.x; s.y += v.y; s.z += v.z; s.w += v.w;
        }
        tm4[(size_t)j * (TSLICE / 4) + idx] = s;
    }
}

// ---------------- K4b: final reduce over 64 slices + Horner -> h[b][r] ----------------
__global__ void __launch_bounds__(256) k_reduce_b(const float* __restrict__ t_mid,
                                                  float* __restrict__ h) {
    int i3q = blockIdx.x * 256 + threadIdx.x;   // 0..1023 (float4 index into [b][r])
    const float4* tm4 = (const float4*)t_mid;
    float4 tn[NDEG];
#pragma unroll
    for (int n = 0; n < NDEG; ++n) tn[n] = make_float4(0.f, 0.f, 0.f, 0.f);
    for (int j = 0; j < 64; ++j) {
#pragma unroll
        for (int n = 0; n < NDEG; ++n) {
            float4 v = tm4[(size_t)j * (TSLICE / 4) + n * 1024 + i3q];
            tn[n].x += v.x; tn[n].y += v.y; tn[n].z += v.z; tn[n].w += v.w;
        }
    }
    float4 hh = tn[0];
#pragma unroll
    for (int n = 1; n < NDEG; ++n) {
        hh.x = fmaf(tn[n].x, hh.x, hh.x);
        hh.y = fmaf(tn[n].y, hh.y, hh.y);
        hh.z = fmaf(tn[n].z, hh.z, hh.z);
        hh.w = fmaf(tn[n].w, hh.w, hh.w);
    }
    ((float4*)h)[i3q] = hh;
}

// ---------------- K5: out[b][s] = beta[s] + sum_r h[b][r]*C[s][r], 8-way b-split ----
__global__ void __launch_bounds__(256) k_out(const float* __restrict__ h,
                                             const float* __restrict__ Cm,
                                             const float* __restrict__ beta,
                                             float* __restrict__ out) {
    int tid = threadIdx.x;
    int s   = (blockIdx.x >> 1) * 64 + (tid & 63);
    int bg  = __builtin_amdgcn_readfirstlane((blockIdx.x & 1) * 4 + (tid >> 6));
    int b0  = bg * 4;

    float acc[4] = {0.f, 0.f, 0.f, 0.f};
    const float4* Cr = (const float4*)(Cm + (size_t)s * RDIM);
    const float* hb = h + b0 * RDIM;               // wave-uniform base -> s_load

#pragma unroll 8
    for (int rc = 0; rc < RDIM / 4; ++rc) {
        float4 c = Cr[rc];
#pragma unroll
        for (int j = 0; j < 4; ++j) {
            const float* hr = hb + j * RDIM + rc * 4;
            float a = acc[j];
            a = fmaf(c.x, hr[0], a);
            a = fmaf(c.y, hr[1], a);
            a = fmaf(c.z, hr[2], a);
            a = fmaf(c.w, hr[3], a);
            acc[j] = a;
        }
    }
    float bt = beta[s];
#pragma unroll
    for (int j = 0; j < 4; ++j)
        out[(size_t)(b0 + j) * SDIM + s] = acc[j] + bt;
}

extern "C" void kernel_launch(void* const* d_in, const int* in_sizes, int n_in,
                              void* d_out, int out_size, void* d_ws, size_t ws_size,
                              hipStream_t stream) {
    const float* x     = (const float*)d_in[0];
    const float* U     = (const float*)d_in[1];
    const float* Cm    = (const float*)d_in[2];
    const float* beta  = (const float*)d_in[3];
    const float* gamma = (const float*)d_in[4];
    const float* bnb   = (const float*)d_in[5];
    float* out = (float*)d_out;

    char* ws = (char*)d_ws;
    size_t off = 0;
    float* stats   = (float*)(ws + off); off += 256;
    float* partial = (float*)(ws + off); off += NSTATB * 2 * 4;
    float* zT      = (float*)(ws + off); off += (size_t)BDIM * SDIM * 4;        // 8 MB
    float* t_part  = (float*)(ws + off); off += (size_t)NCHUNK * TSLICE * 4;    // 32 MB
    float* t_mid   = (float*)(ws + off); off += (size_t)64 * TSLICE * 4;        // 4 MB
    float* h       = (float*)(ws + off); off += (size_t)BDIM * RDIM * 4;        // 16 KB

    k_stats<<<NSTATB, 256, 0, stream>>>(x, partial);
    k_stats_fin<<<1, 256, 0, stream>>>(partial, stats);
    k_norm_t<<<SDIM / 64, 256, 0, stream>>>(x, gamma, bnb, stats, zT);
    dim3 g3(NCHUNK, NDEG);
    k_gemm_t<<<g3, 256, 0, stream>>>(zT, U, t_part);
    dim3 g4(64, 4);
    k_reduce_a<<<g4, 256, 0, stream>>>(t_part, t_mid);
    k_reduce_b<<<4, 256, 0, stream>>>(t_mid, h);
    k_out<<<2048, 256, 0, stream>>>(h, Cm, beta, out);
}